// Round 13
// baseline (525.980 us; speedup 1.0000x reference)
//
#include <hip/hip_runtime.h>

#define NF 512
#define MB 2048
#define CSTRIDE 256   // padded per-step pair stride for cA/cB (float4-pairs)
#define PL (NF * NF)  // bf16 elements per 512x512 plane
#define LDT 72
#define NBLK 512

typedef __attribute__((ext_vector_type(8))) short bf16x8;
typedef __attribute__((ext_vector_type(4))) float f32x4;
typedef __attribute__((ext_vector_type(4))) int i32x4;

__device__ __forceinline__ float2 cmul(float2 a, float2 b) {
  return make_float2(fmaf(a.x, b.x, -(a.y * b.y)), fmaf(a.x, b.y, a.y * b.x));
}
__device__ __forceinline__ float2 cfma(float2 a, float2 b, float2 c) {
  return make_float2(fmaf(a.x, b.x, fmaf(-a.y, b.y, c.x)),
                     fmaf(a.x, b.y, fmaf(a.y, b.x, c.y)));
}
__device__ __forceinline__ unsigned short f2bf(float f) {
  union { float f; unsigned u; } v; v.f = f;
  unsigned r = v.u + 0x7FFF + ((v.u >> 16) & 1);
  return (unsigned short)(r >> 16);
}

// ---- software grid barrier ----
// Arrival: ONE device-scope RMW per block. Spin: agent-scope atomic LOAD (shareable,
// no cache-line ownership ping-pong — R12's atomicAdd(p,0) poll was 512 serialized
// RMWs per round and cost ~60us/barrier). Bounded spin: fail visibly, never hang.
__device__ __forceinline__ void gbar(unsigned* cnt, int idx) {
  __syncthreads();
  if (threadIdx.x == 0) {
    __threadfence();                           // release my writes
    __hip_atomic_fetch_add(&cnt[idx * 32], 1u, __ATOMIC_RELEASE,
                           __HIP_MEMORY_SCOPE_AGENT);
    int guard = 0;
    while (__hip_atomic_load(&cnt[idx * 32], __ATOMIC_ACQUIRE,
                             __HIP_MEMORY_SCOPE_AGENT) < (unsigned)NBLK) {
      __builtin_amdgcn_s_sleep(4);
      if (++guard > (1 << 24)) break;
    }
    __threadfence();                           // acquire others' writes
  }
  __syncthreads();
}

__global__ __launch_bounds__(64) void init_kernel(unsigned* cnt) {
  cnt[threadIdx.x * 4] = 0u;
  cnt[threadIdx.x * 4 + 1] = 0u;
  cnt[threadIdx.x * 4 + 2] = 0u;
  cnt[threadIdx.x * 4 + 3] = 0u;
}

// ---- mesh core (R6/R10-proven) ----
struct MZS { float2 a0, b0, a1, b1; };

__device__ __forceinline__ void mzi_apply(const float4& k0, const float4& k1,
                                          float2& a, float2& b) {
  float2 c1 = make_float2(k0.x, k0.y), c2 = make_float2(k0.z, k0.w);
  float2 c3 = make_float2(k1.x, k1.y), c4 = make_float2(k1.z, k1.w);
  float2 na = cfma(c2, b, cmul(c1, a));
  float2 nb = cfma(c4, b, cmul(c3, a));
  a = na; b = nb;
}
__device__ __forceinline__ float2 mzi_bnd(const float4& k0, const float4& k1,
                                          float2& a, float2 b, bool en) {
  float2 d1 = make_float2(k0.x, k0.y), d2 = make_float2(k0.z, k0.w);
  float2 d3 = make_float2(k1.x, k1.y), d4 = make_float2(k1.z, k1.w);
  float2 na = cfma(d2, b, cmul(d1, a));
  float2 nb = cfma(d4, b, cmul(d3, a));
  if (en) a = na;
  return en ? nb : make_float2(0.f, 0.f);
}
__device__ __forceinline__ void load_bank(float4 (&K)[8],
    const float4* __restrict__ cA, const float4* __restrict__ cB, int l, int q0)
{
  const float4* pa = cA + (size_t)l * (CSTRIDE * 2) + (size_t)q0 * 2;
  const float4* pb = cB + (size_t)l * (CSTRIDE * 2) + (size_t)q0 * 2;
  K[0] = pa[0]; K[1] = pa[1]; K[2] = pa[2]; K[3] = pa[3];
  K[4] = pb[0]; K[5] = pb[1]; K[6] = pb[2]; K[7] = pb[3];
}
__device__ __forceinline__ void step_state(const float4 (&K)[8], int L, bool hasBnd,
                                           MZS& s)
{
  mzi_apply(K[0], K[1], s.a0, s.b0);
  mzi_apply(K[2], K[3], s.a1, s.b1);
  float xnx = __shfl_down(s.a0.x, 1);
  float xny = __shfl_down(s.a0.y, 1);
  float2 xn = (L == 63) ? make_float2(0.f, 0.f) : make_float2(xnx, xny);
  float2 nbo = mzi_bnd(K[6], K[7], s.b1, xn, hasBnd);
  mzi_apply(K[4], K[5], s.b0, s.a1);
  float px = __shfl_up(nbo.x, 1);
  float py = __shfl_up(nbo.y, 1);
  if (L > 0) s.a0 = make_float2(px, py);
}

// ---- product tile: D[a][b] = sum_k A[a][k]*B[b][k] (complex, bf16), writes out[a*NF+b] ----
__device__ void prod_tile(
    const unsigned short* __restrict__ Agr, const unsigned short* __restrict__ Agi,
    const unsigned short* __restrict__ Bgr, const unsigned short* __restrict__ Bgi,
    unsigned short* __restrict__ Or, unsigned short* __restrict__ Oi,
    int bm, int bn, int klo, int khi, int tid,
    unsigned short (*Ars)[LDT], unsigned short (*Ais)[LDT],
    unsigned short (*Brs)[LDT], unsigned short (*Bis)[LDT])
{
  const int w = tid >> 6, wm = w & 1, wn = w >> 1, lane = tid & 63;
  f32x4 acc_r[2], acc_i[2];
#pragma unroll
  for (int nf = 0; nf < 2; ++nf) {
    acc_r[nf] = (f32x4){0.f, 0.f, 0.f, 0.f};
    acc_i[nf] = (f32x4){0.f, 0.f, 0.f, 0.f};
  }
  const int sar = tid >> 3, sak = (tid & 7) * 8;
  const int sbr = tid >> 2, sbk = (tid & 3) * 16;

  for (int k0 = klo; k0 < khi; k0 += 64) {
    const uint4* gar = (const uint4*)(Agr + (size_t)(bm + sar) * NF + k0 + sak);
    const uint4* gai = (const uint4*)(Agi + (size_t)(bm + sar) * NF + k0 + sak);
    const uint4* gbr = (const uint4*)(Bgr + (size_t)(bn + sbr) * NF + k0 + sbk);
    const uint4* gbi = (const uint4*)(Bgi + (size_t)(bn + sbr) * NF + k0 + sbk);
    uint4 ar = gar[0];
    uint4 ai = gai[0];
    uint4 br0 = gbr[0], br1 = gbr[1];
    uint4 bi0 = gbi[0], bi1 = gbi[1];

    __syncthreads();

    *(uint4*)&Ars[sar][sak]     = ar;
    *(uint4*)&Ais[sar][sak]     = ai;
    *(uint4*)&Brs[sbr][sbk]     = br0;
    *(uint4*)&Brs[sbr][sbk + 8] = br1;
    *(uint4*)&Bis[sbr][sbk]     = bi0;
    *(uint4*)&Bis[sbr][sbk + 8] = bi1;

    __syncthreads();

#pragma unroll
    for (int kk = 0; kk < 2; ++kk) {
      const int ko = kk * 32 + (lane >> 4) * 8;
      bf16x8 afr = *(const bf16x8*)&Ars[wm * 16 + (lane & 15)][ko];
      bf16x8 afi = *(const bf16x8*)&Ais[wm * 16 + (lane & 15)][ko];
      i32x4 neg = (i32x4)afi ^ (int)0x80008000;
      bf16x8 afin = (bf16x8)neg;
#pragma unroll
      for (int nf = 0; nf < 2; ++nf) {
        bf16x8 bfr = *(const bf16x8*)&Brs[wn * 32 + nf * 16 + (lane & 15)][ko];
        bf16x8 bfi = *(const bf16x8*)&Bis[wn * 32 + nf * 16 + (lane & 15)][ko];
        acc_r[nf] = __builtin_amdgcn_mfma_f32_16x16x32_bf16(afr,  bfr, acc_r[nf], 0, 0, 0);
        acc_r[nf] = __builtin_amdgcn_mfma_f32_16x16x32_bf16(afin, bfi, acc_r[nf], 0, 0, 0);
        acc_i[nf] = __builtin_amdgcn_mfma_f32_16x16x32_bf16(afr,  bfi, acc_i[nf], 0, 0, 0);
        acc_i[nf] = __builtin_amdgcn_mfma_f32_16x16x32_bf16(afi,  bfr, acc_i[nf], 0, 0, 0);
      }
    }
  }

  const int dn0 = bn + wn * 32 + (lane & 15);
  const int dm0 = bm + wm * 16 + (lane >> 4) * 4;
#pragma unroll
  for (int nf = 0; nf < 2; ++nf) {
    const int n = dn0 + nf * 16;
#pragma unroll
    for (int r = 0; r < 4; ++r) {
      Or[(size_t)(dm0 + r) * NF + n] = f2bf(acc_r[nf][r]);
      Oi[(size_t)(dm0 + r) * NF + n] = f2bf(acc_i[nf][r]);
    }
  }
}

// ---- the fused persistent kernel (R12 structure, fixed barrier) ----
__global__ __launch_bounds__(256) void fused_kernel(
    const float* __restrict__ a0, const float* __restrict__ a1,
    const float* __restrict__ b0, const float* __restrict__ b1,
    const float4* __restrict__ Xf, const float* __restrict__ omega,
    float4* __restrict__ cA, float4* __restrict__ cB,
    unsigned short* __restrict__ Xr, unsigned short* __restrict__ Xi,
    unsigned short* __restrict__ Cb, unsigned short* __restrict__ Wp,
    unsigned short* __restrict__ Vp, unsigned short* __restrict__ Up,
    unsigned* __restrict__ cnt, float2* __restrict__ Y)
{
  __shared__ __align__(16) unsigned short Ars[32][LDT];
  __shared__ __align__(16) unsigned short Ais[32][LDT];
  __shared__ __align__(16) unsigned short Brs[64][LDT];
  __shared__ __align__(16) unsigned short Bis[64][LDT];

  const int bid = blockIdx.x, tid = threadIdx.x;

  // ============ P1: coeffs + X -> bf16 planes ============
  if (bid < 64) {
    const int l = bid;
    {
      float ang0 = a0[l * 256 + tid], ang1 = a1[l * 256 + tid];
      float se, ce, st, ct;
      sincosf(ang0, &se, &ce);
      sincosf(ang1, &st, &ct);
      float2 ephi = make_float2(ce, se);
      float2 tt = make_float2(0.5f * (ct - 1.0f), 0.5f * st);
      float2 uu = make_float2(0.5f * (ct + 1.0f), 0.5f * st);
      float2 C1 = cmul(ephi, tt);
      float2 C2 = make_float2(-uu.y, uu.x);
      float2 eu = cmul(ephi, uu);
      float2 C3 = make_float2(-eu.y, eu.x);
      float2 C4 = make_float2(-tt.x, -tt.y);
      float4* dst = cA + (size_t)(l * CSTRIDE + tid) * 2;
      dst[0] = make_float4(C1.x, C1.y, C2.x, C2.y);
      dst[1] = make_float4(C3.x, C3.y, C4.x, C4.y);
    }
    if (tid < 255) {
      float ang0 = b0[l * 255 + tid], ang1 = b1[l * 255 + tid];
      float se, ce, st, ct;
      sincosf(ang0, &se, &ce);
      sincosf(ang1, &st, &ct);
      float2 ephi = make_float2(ce, se);
      float2 tt = make_float2(0.5f * (ct - 1.0f), 0.5f * st);
      float2 uu = make_float2(0.5f * (ct + 1.0f), 0.5f * st);
      float2 C1 = cmul(ephi, tt);
      float2 C2 = make_float2(-uu.y, uu.x);
      float2 eu = cmul(ephi, uu);
      float2 C3 = make_float2(-eu.y, eu.x);
      float2 C4 = make_float2(-tt.x, -tt.y);
      float4* dst = cB + (size_t)(l * CSTRIDE + tid) * 2;
      dst[0] = make_float4(C1.x, C1.y, C2.x, C2.y);
      dst[1] = make_float4(C3.x, C3.y, C4.x, C4.y);
    } else {
      float4* dst = cB + (size_t)(l * CSTRIDE + 255) * 2;
      dst[0] = make_float4(0.f, 0.f, 0.f, 0.f);
      dst[1] = make_float4(0.f, 0.f, 0.f, 0.f);
    }
  }
  {
    const int t0 = bid * 256 + tid;
#pragma unroll
    for (int s = 0; s < 2; ++s) {
      const int qi = t0 + s * 131072;
      float4 v0 = Xf[(size_t)qi * 2];
      float4 v1 = Xf[(size_t)qi * 2 + 1];
      ushort4 r, im;
      r.x = f2bf(v0.x); im.x = f2bf(v0.y);
      r.y = f2bf(v0.z); im.y = f2bf(v0.w);
      r.z = f2bf(v1.x); im.z = f2bf(v1.y);
      r.w = f2bf(v1.z); im.w = f2bf(v1.w);
      *(ushort4*)(Xr + (size_t)qi * 4) = r;
      *(ushort4*)(Xi + (size_t)qi * 4) = im;
    }
  }
  gbar(cnt, 0);

  // ============ P2: 8 chunks x 8 steps; wave g -> (chunk m, col-pair c) ============
  {
    const int wid = tid >> 6, L = tid & 63;
    const int g = bid * 4 + wid;                 // 0..2047
    const int m = g >> 8;
    const int cp = g & 255;
    const int c = (cp & 7) * 32 + (cp >> 3);
    int ws = c - 63; ws = ws < 0 ? 0 : (ws > 128 ? 128 : ws);
    const int q0 = ws + 2 * L, q1 = q0 + 1;
    const bool hasBnd = (q1 < 255);

    MZS s0, s1;
    s0.a0 = make_float2((q0 == c) ? 1.f : 0.f, 0.f);
    s0.b0 = make_float2(0.f, 0.f);
    s0.a1 = make_float2((q1 == c) ? 1.f : 0.f, 0.f);
    s0.b1 = make_float2(0.f, 0.f);
    s1.a0 = make_float2(0.f, 0.f);
    s1.b0 = make_float2((q0 == c) ? 1.f : 0.f, 0.f);
    s1.a1 = make_float2(0.f, 0.f);
    s1.b1 = make_float2((q1 == c) ? 1.f : 0.f, 0.f);

    const int l0 = m * 8;
    float4 K0[8], K1[8];
    load_bank(K0, cA, cB, l0 + 0, q0);
    load_bank(K1, cA, cB, l0 + 1, q0);
#pragma unroll 1
    for (int i = 0; i < 6; i += 2) {
      step_state(K0, L, hasBnd, s0); step_state(K0, L, hasBnd, s1);
      load_bank(K0, cA, cB, l0 + i + 2, q0);
      step_state(K1, L, hasBnd, s0); step_state(K1, L, hasBnd, s1);
      load_bank(K1, cA, cB, l0 + i + 3, q0);
    }
    step_state(K0, L, hasBnd, s0); step_state(K0, L, hasBnd, s1);
    step_state(K1, L, hasBnd, s0); step_state(K1, L, hasBnd, s1);

    unsigned short* Pr = Cb + (size_t)m * 2 * PL;
    unsigned short* Pi = Pr + PL;
    const float2 v0[4] = {s0.a0, s0.b0, s0.a1, s0.b1};
    const float2 v1[4] = {s1.a0, s1.b0, s1.a1, s1.b1};
    if ((m & 1) == 0) {
      const int j0 = 2 * c, j1 = 2 * c + 1;
      const int col0 = 2 * q0;
      ushort4 r0, i0, r1, i1;
      r0.x = f2bf(v0[0].x); r0.y = f2bf(v0[1].x); r0.z = f2bf(v0[2].x); r0.w = f2bf(v0[3].x);
      i0.x = f2bf(v0[0].y); i0.y = f2bf(v0[1].y); i0.z = f2bf(v0[2].y); i0.w = f2bf(v0[3].y);
      r1.x = f2bf(v1[0].x); r1.y = f2bf(v1[1].x); r1.z = f2bf(v1[2].x); r1.w = f2bf(v1[3].x);
      i1.x = f2bf(v1[0].y); i1.y = f2bf(v1[1].y); i1.z = f2bf(v1[2].y); i1.w = f2bf(v1[3].y);
      *(ushort4*)&Pr[(size_t)j0 * NF + col0] = r0;
      *(ushort4*)&Pi[(size_t)j0 * NF + col0] = i0;
      *(ushort4*)&Pr[(size_t)j1 * NF + col0] = r1;
      *(ushort4*)&Pi[(size_t)j1 * NF + col0] = i1;
      const int z0 = (col0 + 256) & 511;
      const int z1 = (col0 + 258) & 511;
      const ushort2 zz = make_ushort2(0, 0);
      *(ushort2*)&Pr[(size_t)j0 * NF + z0] = zz;
      *(ushort2*)&Pr[(size_t)j0 * NF + z1] = zz;
      *(ushort2*)&Pi[(size_t)j0 * NF + z0] = zz;
      *(ushort2*)&Pi[(size_t)j0 * NF + z1] = zz;
      *(ushort2*)&Pr[(size_t)j1 * NF + z0] = zz;
      *(ushort2*)&Pr[(size_t)j1 * NF + z1] = zz;
      *(ushort2*)&Pi[(size_t)j1 * NF + z0] = zz;
      *(ushort2*)&Pi[(size_t)j1 * NF + z1] = zz;
    } else {
      unsigned* nr32 = (unsigned*)Pr;
      unsigned* ni32 = (unsigned*)Pi;
      const int rows[4] = {2 * q0, 2 * q0 + 1, 2 * q1, 2 * q1 + 1};
#pragma unroll
      for (int e = 0; e < 4; ++e) {
        unsigned pr = (unsigned)f2bf(v0[e].x) | ((unsigned)f2bf(v1[e].x) << 16);
        unsigned pi = (unsigned)f2bf(v0[e].y) | ((unsigned)f2bf(v1[e].y) << 16);
        nr32[(size_t)rows[e] * (NF / 2) + c] = pr;
        ni32[(size_t)rows[e] * (NF / 2) + c] = pi;
      }
#pragma unroll
      for (int e = 0; e < 4; ++e) {
        const int row = (2 * ws + 256 + 4 * L + e) & 511;
        nr32[(size_t)row * (NF / 2) + c] = 0u;
        ni32[(size_t)row * (NF / 2) + c] = 0u;
      }
    }
  }
  gbar(cnt, 1);

  // ============ P3: L1 — W_z = C_{2z+1} · C_{2z}; z even -> T out, z odd -> N out ============
  {
    const int z = bid >> 7;
    const int t = bid & 127;
    const int bm = (t >> 3) * 32, bn = (t & 7) * 64;
    const unsigned short* CT = Cb + (size_t)(2 * z) * 2 * PL;
    const unsigned short* CN = Cb + (size_t)(2 * z + 1) * 2 * PL;
    unsigned short* O = Wp + (size_t)z * 2 * PL;
    const int hw = 17 + 2;
    const unsigned short* A; const unsigned short* B;
    if ((z & 1) == 0) { A = CT; B = CN; }
    else             { A = CN; B = CT; }
    int klo = bm - hw; { int u = bn - hw; if (u > klo) klo = u; }
    if (klo < 0) klo = 0; klo &= ~63;
    int khi = bm + 32 + hw; { int u = bn + 64 + hw; if (u < khi) khi = u; }
    if (khi > NF) khi = NF; khi = (khi + 63) & ~63;
    prod_tile(A, A + PL, B, B + PL, O, O + PL, bm, bn, klo, khi, tid,
              Ars, Ais, Brs, Bis);
  }
  gbar(cnt, 2);

  // ============ P4: L2 — V_y = W_{2y+1} · W_{2y}; V0 -> T, V1 -> N ============
  if (bid < 256) {
    const int y = bid >> 7;
    const int t = bid & 127;
    const int bm = (t >> 3) * 32, bn = (t & 7) * 64;
    const unsigned short* WT = Wp + (size_t)(2 * y) * 2 * PL;
    const unsigned short* WN = Wp + (size_t)(2 * y + 1) * 2 * PL;
    unsigned short* O = Vp + (size_t)y * 2 * PL;
    const int hw = 34 + 4;
    const unsigned short* A; const unsigned short* B;
    if (y == 0) { A = WT; B = WN; }
    else        { A = WN; B = WT; }
    int klo = bm - hw; { int u = bn - hw; if (u > klo) klo = u; }
    if (klo < 0) klo = 0; klo &= ~63;
    int khi = bm + 32 + hw; { int u = bn + 64 + hw; if (u < khi) khi = u; }
    if (khi > NF) khi = NF; khi = (khi + 63) & ~63;
    prod_tile(A, A + PL, B, B + PL, O, O + PL, bm, bn, klo, khi, tid,
              Ars, Ais, Brs, Bis);
  }
  gbar(cnt, 3);

  // ============ P5: L3 — U = V1 · V0 (N out) ============
  if (bid < 128) {
    const int t = bid;
    const int bm = (t >> 3) * 32, bn = (t & 7) * 64;
    const unsigned short* V0T = Vp;
    const unsigned short* V1N = Vp + (size_t)2 * PL;
    const int hw = 68 + 4;
    int klo = bm - hw; { int u = bn - hw; if (u > klo) klo = u; }
    if (klo < 0) klo = 0; klo &= ~63;
    int khi = bm + 32 + hw; { int u = bn + 64 + hw; if (u < khi) khi = u; }
    if (khi > NF) khi = NF; khi = (khi + 63) & ~63;
    prod_tile(V1N, V1N + PL, V0T, V0T + PL, Up, Up + PL, bm, bn, klo, khi, tid,
              Ars, Ais, Brs, Bis);
  }
  gbar(cnt, 4);

  // ============ P6: final — Y[r][n] = (sum_j X[r][j] U[n][j]) * e^{i w_n} ============
  {
    const unsigned short* Ur = Up;
    const unsigned short* Ui = Up + PL;
    const int w = tid >> 6, wm = w & 1, wn = w >> 1;
    const int lane = tid & 63;
    const int bm = (bid >> 3) * 32;
    const int bn = (bid & 7) * 64;

    int klo = bn - 140; if (klo < 0) klo = 0; klo &= ~63;
    int khi = bn + 204; if (khi > NF) khi = NF; khi = (khi + 63) & ~63;

    f32x4 acc_r[2], acc_i[2];
#pragma unroll
    for (int nf = 0; nf < 2; ++nf) {
      acc_r[nf] = (f32x4){0.f, 0.f, 0.f, 0.f};
      acc_i[nf] = (f32x4){0.f, 0.f, 0.f, 0.f};
    }
    const int sar = tid >> 3, sak = (tid & 7) * 8;
    const int sbr = tid >> 2, sbk = (tid & 3) * 16;

    for (int k0 = klo; k0 < khi; k0 += 64) {
      const uint4* gar = (const uint4*)(Xr + (size_t)(bm + sar) * NF + k0 + sak);
      const uint4* gai = (const uint4*)(Xi + (size_t)(bm + sar) * NF + k0 + sak);
      const uint4* gbr = (const uint4*)(Ur + (size_t)(bn + sbr) * NF + k0 + sbk);
      const uint4* gbi = (const uint4*)(Ui + (size_t)(bn + sbr) * NF + k0 + sbk);
      uint4 ar = gar[0];
      uint4 ai = gai[0];
      uint4 br0 = gbr[0], br1 = gbr[1];
      uint4 bi0 = gbi[0], bi1 = gbi[1];

      __syncthreads();

      *(uint4*)&Ars[sar][sak]     = ar;
      *(uint4*)&Ais[sar][sak]     = ai;
      *(uint4*)&Brs[sbr][sbk]     = br0;
      *(uint4*)&Brs[sbr][sbk + 8] = br1;
      *(uint4*)&Bis[sbr][sbk]     = bi0;
      *(uint4*)&Bis[sbr][sbk + 8] = bi1;

      __syncthreads();

#pragma unroll
      for (int kk = 0; kk < 2; ++kk) {
        const int ko = kk * 32 + (lane >> 4) * 8;
        bf16x8 afr = *(const bf16x8*)&Ars[wm * 16 + (lane & 15)][ko];
        bf16x8 afi = *(const bf16x8*)&Ais[wm * 16 + (lane & 15)][ko];
        i32x4 neg = (i32x4)afi ^ (int)0x80008000;
        bf16x8 afin = (bf16x8)neg;
#pragma unroll
        for (int nf = 0; nf < 2; ++nf) {
          bf16x8 bfr = *(const bf16x8*)&Brs[wn * 32 + nf * 16 + (lane & 15)][ko];
          bf16x8 bfi = *(const bf16x8*)&Bis[wn * 32 + nf * 16 + (lane & 15)][ko];
          acc_r[nf] = __builtin_amdgcn_mfma_f32_16x16x32_bf16(afr,  bfr, acc_r[nf], 0, 0, 0);
          acc_r[nf] = __builtin_amdgcn_mfma_f32_16x16x32_bf16(afin, bfi, acc_r[nf], 0, 0, 0);
          acc_i[nf] = __builtin_amdgcn_mfma_f32_16x16x32_bf16(afr,  bfi, acc_i[nf], 0, 0, 0);
          acc_i[nf] = __builtin_amdgcn_mfma_f32_16x16x32_bf16(afi,  bfr, acc_i[nf], 0, 0, 0);
        }
      }
    }

    const int dn0 = bn + wn * 32 + (lane & 15);
    const int dm0 = bm + wm * 16 + (lane >> 4) * 4;
#pragma unroll
    for (int nf = 0; nf < 2; ++nf) {
      const int n = dn0 + nf * 16;
      float sn, cn;
      sincosf(omega[n], &sn, &cn);
#pragma unroll
      for (int r = 0; r < 4; ++r) {
        float yr = acc_r[nf][r], yi = acc_i[nf][r];
        Y[(size_t)(dm0 + r) * NF + n] =
            make_float2(fmaf(yr, cn, -(yi * sn)), fmaf(yr, sn, yi * cn));
      }
    }
  }
}

extern "C" void kernel_launch(void* const* d_in, const int* in_sizes, int n_in,
                              void* d_out, int out_size, void* d_ws, size_t ws_size,
                              hipStream_t stream) {
  const float4* Xf   = (const float4*)d_in[0];
  const float* a0    = (const float*)d_in[1];
  const float* a1    = (const float*)d_in[2];
  const float* b0    = (const float*)d_in[3];
  const float* b1    = (const float*)d_in[4];
  const float* omega = (const float*)d_in[5];

  size_t off = 0;
  float4* cA = (float4*)((char*)d_ws + off); off += (size_t)64 * CSTRIDE * 2 * sizeof(float4);
  float4* cB = (float4*)((char*)d_ws + off); off += (size_t)64 * CSTRIDE * 2 * sizeof(float4);
  unsigned short* Xr = (unsigned short*)((char*)d_ws + off); off += (size_t)MB * NF * 2;
  unsigned short* Xi = (unsigned short*)((char*)d_ws + off); off += (size_t)MB * NF * 2;
  unsigned short* Cb = (unsigned short*)((char*)d_ws + off); off += (size_t)8 * 2 * PL * 2;
  unsigned short* Wp = (unsigned short*)((char*)d_ws + off); off += (size_t)4 * 2 * PL * 2;
  unsigned short* Vp = (unsigned short*)((char*)d_ws + off); off += (size_t)2 * 2 * PL * 2;
  unsigned short* Up = (unsigned short*)((char*)d_ws + off); off += (size_t)1 * 2 * PL * 2;
  unsigned* cnt = (unsigned*)((char*)d_ws + off); off += 4096;
  float2* Y = (float2*)d_out;

  init_kernel<<<1, 64, 0, stream>>>(cnt);
  fused_kernel<<<NBLK, 256, 0, stream>>>(a0, a1, b0, b1, Xf, omega,
                                         cA, cB, Xr, Xi, Cb, Wp, Vp, Up, cnt, Y);
}

// Round 14
// 49.022 us; speedup vs baseline: 10.7294x; 10.7294x over previous
//
#include <hip/hip_runtime.h>

#define NF 512
#define MB 2048
#define CSTRIDE 256   // padded per-step pair stride for cA/cB (float4-pairs)
#define PL (NF * NF)  // bf16 elements per 512x512 plane
#define LDT 72

typedef __attribute__((ext_vector_type(8))) short bf16x8;
typedef __attribute__((ext_vector_type(4))) float f32x4;
typedef __attribute__((ext_vector_type(4))) int i32x4;

__device__ __forceinline__ float2 cmul(float2 a, float2 b) {
  return make_float2(fmaf(a.x, b.x, -(a.y * b.y)), fmaf(a.x, b.y, a.y * b.x));
}
__device__ __forceinline__ float2 cfma(float2 a, float2 b, float2 c) {
  return make_float2(fmaf(a.x, b.x, fmaf(-a.y, b.y, c.x)),
                     fmaf(a.x, b.y, fmaf(a.y, b.x, c.y)));
}
__device__ __forceinline__ unsigned short f2bf(float f) {
  union { float f; unsigned u; } v; v.f = f;
  unsigned r = v.u + 0x7FFF + ((v.u >> 16) & 1);
  return (unsigned short)(r >> 16);
}

// ---------------- K1: coefficients only (incl. cB pair-255 pad zero) ----------------
__global__ __launch_bounds__(256) void prep_kernel(
    const float* __restrict__ a0, const float* __restrict__ a1,
    const float* __restrict__ b0, const float* __restrict__ b1,
    float4* __restrict__ cA, float4* __restrict__ cB)
{
  const int l = blockIdx.x, tid = threadIdx.x;
  {
    float ang0 = a0[l * 256 + tid], ang1 = a1[l * 256 + tid];
    float se, ce, st, ct;
    sincosf(ang0, &se, &ce);
    sincosf(ang1, &st, &ct);
    float2 ephi = make_float2(ce, se);
    float2 tt = make_float2(0.5f * (ct - 1.0f), 0.5f * st);
    float2 uu = make_float2(0.5f * (ct + 1.0f), 0.5f * st);
    float2 C1 = cmul(ephi, tt);
    float2 C2 = make_float2(-uu.y, uu.x);
    float2 eu = cmul(ephi, uu);
    float2 C3 = make_float2(-eu.y, eu.x);
    float2 C4 = make_float2(-tt.x, -tt.y);
    float4* dst = cA + (size_t)(l * CSTRIDE + tid) * 2;
    dst[0] = make_float4(C1.x, C1.y, C2.x, C2.y);
    dst[1] = make_float4(C3.x, C3.y, C4.x, C4.y);
  }
  if (tid < 255) {
    float ang0 = b0[l * 255 + tid], ang1 = b1[l * 255 + tid];
    float se, ce, st, ct;
    sincosf(ang0, &se, &ce);
    sincosf(ang1, &st, &ct);
    float2 ephi = make_float2(ce, se);
    float2 tt = make_float2(0.5f * (ct - 1.0f), 0.5f * st);
    float2 uu = make_float2(0.5f * (ct + 1.0f), 0.5f * st);
    float2 C1 = cmul(ephi, tt);
    float2 C2 = make_float2(-uu.y, uu.x);
    float2 eu = cmul(ephi, uu);
    float2 C3 = make_float2(-eu.y, eu.x);
    float2 C4 = make_float2(-tt.x, -tt.y);
    float4* dst = cB + (size_t)(l * CSTRIDE + tid) * 2;
    dst[0] = make_float4(C1.x, C1.y, C2.x, C2.y);
    dst[1] = make_float4(C3.x, C3.y, C4.x, C4.y);
  } else {
    float4* dst = cB + (size_t)(l * CSTRIDE + 255) * 2;
    dst[0] = make_float4(0.f, 0.f, 0.f, 0.f);
    dst[1] = make_float4(0.f, 0.f, 0.f, 0.f);
  }
}

// ---------------- K2: 2 chunks x 32 steps, ONE column per wave (R5's fastest geometry),
//                      3-bank coeff pipeline, full-column writes (R6 determinism) ----------------
struct MZS { float2 a0, b0, a1, b1; };

__device__ __forceinline__ void mzi_apply(const float4& k0, const float4& k1,
                                          float2& a, float2& b) {
  float2 c1 = make_float2(k0.x, k0.y), c2 = make_float2(k0.z, k0.w);
  float2 c3 = make_float2(k1.x, k1.y), c4 = make_float2(k1.z, k1.w);
  float2 na = cfma(c2, b, cmul(c1, a));
  float2 nb = cfma(c4, b, cmul(c3, a));
  a = na; b = nb;
}
__device__ __forceinline__ float2 mzi_bnd(const float4& k0, const float4& k1,
                                          float2& a, float2 b, bool en) {
  float2 d1 = make_float2(k0.x, k0.y), d2 = make_float2(k0.z, k0.w);
  float2 d3 = make_float2(k1.x, k1.y), d4 = make_float2(k1.z, k1.w);
  float2 na = cfma(d2, b, cmul(d1, a));
  float2 nb = cfma(d4, b, cmul(d3, a));
  if (en) a = na;
  return en ? nb : make_float2(0.f, 0.f);
}
__device__ __forceinline__ void load_bank(float4 (&K)[8],
    const float4* __restrict__ cA, const float4* __restrict__ cB, int l, int q0)
{
  const float4* pa = cA + (size_t)l * (CSTRIDE * 2) + (size_t)q0 * 2;
  const float4* pb = cB + (size_t)l * (CSTRIDE * 2) + (size_t)q0 * 2;
  K[0] = pa[0]; K[1] = pa[1]; K[2] = pa[2]; K[3] = pa[3];
  K[4] = pb[0]; K[5] = pb[1]; K[6] = pb[2]; K[7] = pb[3];
}
__device__ __forceinline__ void step_state(const float4 (&K)[8], int L, bool hasBnd,
                                           MZS& s)
{
  mzi_apply(K[0], K[1], s.a0, s.b0);
  mzi_apply(K[2], K[3], s.a1, s.b1);
  float xnx = __shfl_down(s.a0.x, 1);
  float xny = __shfl_down(s.a0.y, 1);
  float2 xn = (L == 63) ? make_float2(0.f, 0.f) : make_float2(xnx, xny);
  float2 nbo = mzi_bnd(K[6], K[7], s.b1, xn, hasBnd);
  mzi_apply(K[4], K[5], s.b0, s.a1);
  float px = __shfl_up(nbo.x, 1);
  float py = __shfl_up(nbo.y, 1);
  if (L > 0) s.a0 = make_float2(px, py);
}

__global__ __launch_bounds__(64) void chunk_mesh(
    const float4* __restrict__ cA, const float4* __restrict__ cB,
    unsigned short* __restrict__ Cb)     // 2 chunks x [re PL][im PL]
{
  const int bid = blockIdx.x;                  // 0..1023
  const int m = bid >> 9;                      // chunk (steps 32m..32m+31)
  const int cb = bid & 511;
  const int j = (cb & 7) * 64 + (cb >> 3);     // bijective XCD swizzle (512 = 8*64)
  const int L = threadIdx.x;
  const int p0 = j >> 1;
  int ws = p0 - 63; ws = ws < 0 ? 0 : (ws > 128 ? 128 : ws);
  const int q0 = ws + 2 * L, q1 = q0 + 1;
  const bool hasBnd = (q1 < 255);

  MZS s;
  s.a0 = make_float2((2 * q0     == j) ? 1.f : 0.f, 0.f);
  s.b0 = make_float2((2 * q0 + 1 == j) ? 1.f : 0.f, 0.f);
  s.a1 = make_float2((2 * q1     == j) ? 1.f : 0.f, 0.f);
  s.b1 = make_float2((2 * q1 + 1 == j) ? 1.f : 0.f, 0.f);

  const int l0 = m * 32;
  float4 K0[8], K1[8], K2[8];
  load_bank(K0, cA, cB, l0 + 0, q0);
  load_bank(K1, cA, cB, l0 + 1, q0);
  load_bank(K2, cA, cB, l0 + 2, q0);

#pragma unroll 1
  for (int i = 0; i < 30; i += 3) {
    step_state(K0, L, hasBnd, s);
    load_bank(K0, cA, cB, l0 + ((i + 3 < 32) ? i + 3 : 31), q0);
    step_state(K1, L, hasBnd, s);
    load_bank(K1, cA, cB, l0 + ((i + 4 < 32) ? i + 4 : 31), q0);
    step_state(K2, L, hasBnd, s);
    load_bank(K2, cA, cB, l0 + ((i + 5 < 32) ? i + 5 : 31), q0);
  }
  step_state(K0, L, hasBnd, s);                // step 30
  step_state(K1, L, hasBnd, s);                // step 31

  // full-column write: 4 in-window rows + 4 complement-zero rows per lane (R6 pattern)
  unsigned short* Cr = Cb + (size_t)m * 2 * PL;
  unsigned short* Ci = Cr + PL;
  const int rows[4] = {2 * q0, 2 * q0 + 1, 2 * q1, 2 * q1 + 1};
  const float2 vals[4] = {s.a0, s.b0, s.a1, s.b1};
#pragma unroll
  for (int e = 0; e < 4; ++e) {
    Cr[(size_t)rows[e] * NF + j] = f2bf(vals[e].x);
    Ci[(size_t)rows[e] * NF + j] = f2bf(vals[e].y);
  }
#pragma unroll
  for (int e = 0; e < 4; ++e) {
    const int row = (2 * ws + 256 + 4 * L + e) & 511;
    Cr[(size_t)row * NF + j] = 0;
    Ci[(size_t)row * NF + j] = 0;
  }
}

// ---------------- banded batch GEMM: Z'[r][n] = sum_j Z[r][j] * C[n][j], |n-j| <= 72 ----------------
// MODE 0: A-input = f32 interleaved X (convert in-register), output bf16 planes.
// MODE 1: A-input = bf16 planes, output f32 complex with exp(i*omega) fused.
template <int MODE>
__global__ __launch_bounds__(256) void gemm_kernel(
    const float2* __restrict__ Xf,
    const unsigned short* __restrict__ Zr, const unsigned short* __restrict__ Zi,
    const unsigned short* __restrict__ Cr, const unsigned short* __restrict__ Ci,
    unsigned short* __restrict__ Or, unsigned short* __restrict__ Oi,
    const float* __restrict__ omega, float2* __restrict__ Y)
{
  __shared__ __align__(16) unsigned short Ars[32][LDT];
  __shared__ __align__(16) unsigned short Ais[32][LDT];
  __shared__ __align__(16) unsigned short Brs[64][LDT];
  __shared__ __align__(16) unsigned short Bis[64][LDT];

  const int tid = threadIdx.x;
  const int w = tid >> 6, wm = w & 1, wn = w >> 1;
  const int lane = tid & 63;
  const int bm = (blockIdx.x >> 3) * 32;
  const int bn = (blockIdx.x & 7) * 64;

  int klo = bn - 72; if (klo < 0) klo = 0; klo &= ~63;
  int khi = bn + 136; if (khi > NF) khi = NF; khi = (khi + 63) & ~63;

  f32x4 acc_r[2], acc_i[2];
#pragma unroll
  for (int nf = 0; nf < 2; ++nf) {
    acc_r[nf] = (f32x4){0.f, 0.f, 0.f, 0.f};
    acc_i[nf] = (f32x4){0.f, 0.f, 0.f, 0.f};
  }
  const int sar = tid >> 3, sak = (tid & 7) * 8;
  const int sbr = tid >> 2, sbk = (tid & 3) * 16;

  for (int k0 = klo; k0 < khi; k0 += 64) {
    ushort4 ar2[2], ai2[2];
    if (MODE == 0) {
      const float4* xs = (const float4*)(Xf + (size_t)(bm + sar) * NF + k0 + sak);
#pragma unroll
      for (int h = 0; h < 2; ++h) {
        float4 v0 = xs[2 * h], v1 = xs[2 * h + 1];
        ar2[h].x = f2bf(v0.x); ai2[h].x = f2bf(v0.y);
        ar2[h].y = f2bf(v0.z); ai2[h].y = f2bf(v0.w);
        ar2[h].z = f2bf(v1.x); ai2[h].z = f2bf(v1.y);
        ar2[h].w = f2bf(v1.z); ai2[h].w = f2bf(v1.w);
      }
    } else {
      const ushort4* gr = (const ushort4*)(Zr + (size_t)(bm + sar) * NF + k0 + sak);
      const ushort4* gi = (const ushort4*)(Zi + (size_t)(bm + sar) * NF + k0 + sak);
      ar2[0] = gr[0]; ar2[1] = gr[1];
      ai2[0] = gi[0]; ai2[1] = gi[1];
    }
    const uint4* gbr = (const uint4*)(Cr + (size_t)(bn + sbr) * NF + k0 + sbk);
    const uint4* gbi = (const uint4*)(Ci + (size_t)(bn + sbr) * NF + k0 + sbk);
    uint4 br0 = gbr[0], br1 = gbr[1];
    uint4 bi0 = gbi[0], bi1 = gbi[1];

    if (k0 > klo) __syncthreads();

    *(ushort4*)&Ars[sar][sak]     = ar2[0];
    *(ushort4*)&Ars[sar][sak + 4] = ar2[1];
    *(ushort4*)&Ais[sar][sak]     = ai2[0];
    *(ushort4*)&Ais[sar][sak + 4] = ai2[1];
    *(uint4*)&Brs[sbr][sbk]       = br0;
    *(uint4*)&Brs[sbr][sbk + 8]   = br1;
    *(uint4*)&Bis[sbr][sbk]       = bi0;
    *(uint4*)&Bis[sbr][sbk + 8]   = bi1;

    __syncthreads();

#pragma unroll
    for (int kk = 0; kk < 2; ++kk) {
      const int ko = kk * 32 + (lane >> 4) * 8;
      bf16x8 afr = *(const bf16x8*)&Ars[wm * 16 + (lane & 15)][ko];
      bf16x8 afi = *(const bf16x8*)&Ais[wm * 16 + (lane & 15)][ko];
      i32x4 neg = (i32x4)afi ^ (int)0x80008000;
      bf16x8 afin = (bf16x8)neg;     // -Ai
#pragma unroll
      for (int nf = 0; nf < 2; ++nf) {
        bf16x8 bfr = *(const bf16x8*)&Brs[wn * 32 + nf * 16 + (lane & 15)][ko];
        bf16x8 bfi = *(const bf16x8*)&Bis[wn * 32 + nf * 16 + (lane & 15)][ko];
        acc_r[nf] = __builtin_amdgcn_mfma_f32_16x16x32_bf16(afr,  bfr, acc_r[nf], 0, 0, 0);
        acc_r[nf] = __builtin_amdgcn_mfma_f32_16x16x32_bf16(afin, bfi, acc_r[nf], 0, 0, 0);
        acc_i[nf] = __builtin_amdgcn_mfma_f32_16x16x32_bf16(afr,  bfi, acc_i[nf], 0, 0, 0);
        acc_i[nf] = __builtin_amdgcn_mfma_f32_16x16x32_bf16(afi,  bfr, acc_i[nf], 0, 0, 0);
      }
    }
  }

  const int dn0 = bn + wn * 32 + (lane & 15);
  const int dm0 = bm + wm * 16 + (lane >> 4) * 4;
#pragma unroll
  for (int nf = 0; nf < 2; ++nf) {
    const int n = dn0 + nf * 16;
    if (MODE == 1) {
      float sn, cn;
      sincosf(omega[n], &sn, &cn);
#pragma unroll
      for (int r = 0; r < 4; ++r) {
        float yr = acc_r[nf][r], yi = acc_i[nf][r];
        Y[(size_t)(dm0 + r) * NF + n] =
            make_float2(fmaf(yr, cn, -(yi * sn)), fmaf(yr, sn, yi * cn));
      }
    } else {
#pragma unroll
      for (int r = 0; r < 4; ++r) {
        Or[(size_t)(dm0 + r) * NF + n] = f2bf(acc_r[nf][r]);
        Oi[(size_t)(dm0 + r) * NF + n] = f2bf(acc_i[nf][r]);
      }
    }
  }
}

extern "C" void kernel_launch(void* const* d_in, const int* in_sizes, int n_in,
                              void* d_out, int out_size, void* d_ws, size_t ws_size,
                              hipStream_t stream) {
  const float2* Xf   = (const float2*)d_in[0];  // (2048, 512) complex f32
  const float* a0    = (const float*)d_in[1];
  const float* a1    = (const float*)d_in[2];
  const float* b0    = (const float*)d_in[3];
  const float* b1    = (const float*)d_in[4];
  const float* omega = (const float*)d_in[5];

  size_t off = 0;
  float4* cA = (float4*)((char*)d_ws + off); off += (size_t)64 * CSTRIDE * 2 * sizeof(float4);
  float4* cB = (float4*)((char*)d_ws + off); off += (size_t)64 * CSTRIDE * 2 * sizeof(float4);
  unsigned short* Cb  = (unsigned short*)((char*)d_ws + off); off += (size_t)2 * 2 * PL * 2;
  unsigned short* Z1r = (unsigned short*)((char*)d_ws + off); off += (size_t)MB * NF * 2;
  unsigned short* Z1i = (unsigned short*)((char*)d_ws + off); off += (size_t)MB * NF * 2;
  float2* Y = (float2*)d_out;

  const unsigned short* C0r = Cb;           const unsigned short* C0i = Cb + PL;
  const unsigned short* C1r = Cb + 2 * PL;  const unsigned short* C1i = Cb + 3 * PL;

  prep_kernel<<<64, 256, 0, stream>>>(a0, a1, b0, b1, cA, cB);
  chunk_mesh<<<1024, 64, 0, stream>>>(cA, cB, Cb);

  const int grid = (MB / 32) * (NF / 64);   // 512 blocks
  gemm_kernel<0><<<grid, 256, 0, stream>>>(Xf, nullptr, nullptr, C0r, C0i,
                                           Z1r, Z1i, omega, Y);
  gemm_kernel<1><<<grid, 256, 0, stream>>>(nullptr, Z1r, Z1i, C1r, C1i,
                                           nullptr, nullptr, omega, Y);
}